// Round 13
// baseline (627.506 us; speedup 1.0000x reference)
//
#include <hip/hip_runtime.h>

#define NGRAPH 100
#define NPER   1000
#define NNODES 100000
#define NEDGES 1600000
#define EPG    16000   // edges per graph

typedef float v2f __attribute__((ext_vector_type(2)));

// DPP-based add of lane (lane ^ pattern) within a 16-lane row; VALU latency.
template <int CTRL>
__device__ __forceinline__ float dpp_add(float x) {
    int yi = __builtin_amdgcn_update_dpp(0, __float_as_int(x), CTRL, 0xF, 0xF, true);
    return x + __int_as_float(yi);
}
#define DPP_XOR1 0xB1   // quad_perm [1,0,3,2]
#define DPP_XOR2 0x4E   // quad_perm [2,3,0,1]
#define DPP_HMIR 0x141  // row_half_mirror
#define DPP_MIR  0x140  // row_mirror

// bf16x2 (packed in u32) -> 2 floats
__device__ __forceinline__ v2f bf2f(unsigned u) {
    v2f r;
    r.x = __uint_as_float(u << 16);
    r.y = __uint_as_float(u & 0xffff0000u);
    return r;
}
// 2 floats -> bf16x2 with round-to-nearest-ish
__device__ __forceinline__ unsigned pkbf(float a, float b) {
    unsigned ua = (__float_as_uint(a) + 0x8000u) >> 16;
    unsigned ub = (__float_as_uint(b) + 0x8000u) & 0xffff0000u;
    return ua | ub;
}

// ==================== utility: zero count + g_acc in one launch ============
__global__ __launch_bounds__(256) void zero2_k(int* __restrict__ count,
                                               float* __restrict__ g_acc) {
    int i = blockIdx.x * 256 + threadIdx.x;
    if (i < NNODES) count[i] = 0;
    if (i < NGRAPH * 96) g_acc[i] = 0.f;
}

// ==================== counting sort of edges by DST ====================
__global__ __launch_bounds__(256) void hist_k(const int* __restrict__ dst,
                                              int* __restrict__ count) {
    int e = blockIdx.x * 256 + threadIdx.x;
    if (e < NEDGES) atomicAdd(&count[dst[e]], 1);
}

__global__ __launch_bounds__(1024) void scan_k(const int* __restrict__ count,
                                               int* __restrict__ offs,
                                               int* __restrict__ cursor) {
    __shared__ int sc[1024];
    int t = threadIdx.x, g = blockIdx.x;
    int v = (t < NPER) ? count[g * NPER + t] : 0;
    sc[t] = v;
    __syncthreads();
    for (int s = 1; s < 1024; s <<= 1) {
        int add = (t >= s) ? sc[t - s] : 0;
        __syncthreads();
        sc[t] += add;
        __syncthreads();
    }
    if (t < NPER) {
        int start = g * EPG + sc[t] - v;   // exclusive
        offs[g * NPER + t]   = start;
        cursor[g * NPER + t] = start;
    }
}

// compressed record: {src*16, etype | elabel<<16}
__global__ __launch_bounds__(256) void scatter_k(
    const int* __restrict__ src, const int* __restrict__ dst,
    const int* __restrict__ et, const int* __restrict__ el,
    int* __restrict__ cursor, int2* __restrict__ sorted2) {
    int e = blockIdx.x * 256 + threadIdx.x;
    if (e >= NEDGES) return;
    int d = dst[e];
    int p = atomicAdd(&cursor[d], 1);
    sorted2[p] = make_int2(src[e] * 16, et[e] | (el[e] << 16));
}

// ==================== node projections: channel-sliced ====================
// grid (391, 7).
// y=0..3: xproj (bf16, pair-packed) channels [y*8,y*8+8) -> one 64B line.
// y=4,5:  psrc/pdst/selfp f32 channel halves -> full 64B line per matrix.
// y=6:    rel tables t1b/t2b (bf16 pairs).
__device__ __forceinline__ float4 dot32x4(const float* __restrict__ w,
                                          const float* hreg, int oc) {
    float4 a = {0.f, 0.f, 0.f, 0.f};
    #pragma unroll 4
    for (int d = 0; d < 32; d++) {
        float4 wv = *(const float4*)(w + d * 32 + oc * 4);
        a.x = fmaf(hreg[d], wv.x, a.x);
        a.y = fmaf(hreg[d], wv.y, a.y);
        a.z = fmaf(hreg[d], wv.z, a.z);
        a.w = fmaf(hreg[d], wv.w, a.w);
    }
    return a;
}

__global__ __launch_bounds__(256, 4) void node_k(
    const float* __restrict__ h, const float* __restrict__ basis_l,
    const float* __restrict__ selfw_l, const float* __restrict__ Aw_l,
    const float* __restrict__ Ab_l, const float* __restrict__ attn_tab,
    uint4* __restrict__ xproj_b, float* __restrict__ psrc,
    float* __restrict__ pdst, float* __restrict__ selfp,
    unsigned* __restrict__ t1b, unsigned* __restrict__ t2b)
{
    const int y = blockIdx.y;
    if (y == 6) {   // rel tables: r = bid*4 + wave, 64 threads per r
        int r = blockIdx.x * 4 + (threadIdx.x >> 6);
        if (r >= 200) return;
        int t = threadIdx.x & 63;
        int o = t & 31;
        bool second = t >= 32;
        const float* at = attn_tab + r * 32;
        const float* W  = Aw_l + (second ? 96*32 : 64*32);
        float acc = second ? 0.f : Ab_l[o];
        #pragma unroll 8
        for (int d = 0; d < 32; d++) acc += at[d] * W[d*32 + o];
        float nb = __shfl_down(acc, 1);
        unsigned u = pkbf(acc, nb);
        if (!(o & 1)) (second ? t2b : t1b)[r*16 + (o >> 1)] = u;
        return;
    }

    __shared__ float w_s[4096];
    if (y < 4) {
        const float4* b4 = (const float4*)basis_l;   // 1024 float4
        float4* w4 = (float4*)w_s;
        for (int k = threadIdx.x; k < 1024; k += 256) w4[k] = b4[k];
    } else {
        const float4* a4 = (const float4*)Aw_l;      // 512 float4 (rows 0..63)
        const float4* s4 = (const float4*)selfw_l;   // 256 float4
        float4* w4 = (float4*)w_s;
        for (int k = threadIdx.x; k < 768; k += 256)
            w4[k] = (k < 512) ? a4[k] : s4[k - 512];
    }
    __syncthreads();

    int n = blockIdx.x * 256 + threadIdx.x;
    if (n >= NNODES) return;

    float hreg[32];
    {
        const float4* hp = (const float4*)(h + n * 32);
        #pragma unroll
        for (int k = 0; k < 8; k++) {
            float4 v = hp[k];
            hreg[4*k+0]=v.x; hreg[4*k+1]=v.y; hreg[4*k+2]=v.z; hreg[4*k+3]=v.w;
        }
    }

    if (y < 4) {
        uint4* xob = xproj_b + n * 16 + y * 4;
        #pragma unroll 1
        for (int ocl = 0; ocl < 2; ocl++) {
            const int oc = y * 2 + ocl;
            float4 p[4];
            #pragma unroll 1
            for (int b = 0; b < 4; b++)
                p[b] = dot32x4(w_s + b * 1024, hreg, oc);
            // pair-pack bf16: dword k = basis k pair {j0,j1}
            xob[ocl*2+0] = make_uint4(pkbf(p[0].x,p[0].y), pkbf(p[1].x,p[1].y),
                                      pkbf(p[2].x,p[2].y), pkbf(p[3].x,p[3].y));
            xob[ocl*2+1] = make_uint4(pkbf(p[0].z,p[0].w), pkbf(p[1].z,p[1].w),
                                      pkbf(p[2].z,p[2].w), pkbf(p[3].z,p[3].w));
        }
    } else {
        const int oc0 = (y - 4) * 4;
        #pragma unroll 1
        for (int m = 0; m < 3; m++) {
            const float* wbase = w_s + (m < 2 ? m * 1024 : 2048);
            float* outp = (m == 0 ? psrc : m == 1 ? pdst : selfp);
            float4 r[4];
            #pragma unroll 1
            for (int ocl = 0; ocl < 4; ocl++)
                r[ocl] = dot32x4(wbase, hreg, oc0 + ocl);
            float* o = outp + n * 32 + oc0 * 4;   // 64B line
            *(float4*)(o +  0) = r[0];
            *(float4*)(o +  4) = r[1];
            *(float4*)(o +  8) = r[2];
            *(float4*)(o + 12) = r[3];
        }
    }
}

// ==================== CSR edge kernel ====================
// wave = 1 node, 4 edge-slots x 16 lanes, 2 ch/lane packed f32.
// R12 diagnosis: gather line-transactions dominate. Cuts: xproj bf16
// (32B->16B per lane, L2-resident), t1/t2 bf16 + wcomp staged in LDS,
// sorted compressed to int2. ~61 -> ~25 lines per wave-iteration.
__global__ __launch_bounds__(256) void edge_csr_k(
    const int2* __restrict__ sorted2, const int* __restrict__ offs,
    const float* __restrict__ psrc, const float* __restrict__ pdst,
    const unsigned* __restrict__ t1b, const unsigned* __restrict__ t2b,
    const uint4* __restrict__ xproj_b, const float* __restrict__ selfp,
    const float* __restrict__ wcomp_l,
    const float* __restrict__ Bw, const float* __restrict__ Bb,
    float* __restrict__ h_next)
{
    __shared__ unsigned t1_s[3200];   // 200 rels x 16 bf16-pairs
    __shared__ unsigned t2_s[3200];
    __shared__ float4   c_s[200];     // w_comp rows (f32)
    {
        const uint4* g1 = (const uint4*)t1b;
        const uint4* g2 = (const uint4*)t2b;
        uint4* s1 = (uint4*)t1_s;
        uint4* s2 = (uint4*)t2_s;
        for (int k = threadIdx.x; k < 800; k += 256) { s1[k] = g1[k]; s2[k] = g2[k]; }
        const float4* cg = (const float4*)wcomp_l;
        if (threadIdx.x < 200) c_s[threadIdx.x] = cg[threadIdx.x];
    }
    __syncthreads();

    // XCD-bijective swizzle: 25000 blocks, 25000 % 8 == 0.
    const int CPX = 25000 / 8;
    int bid = (int)blockIdx.x;
    bid = (bid % 8) * CPX + bid / 8;

    const int wib  = threadIdx.x >> 6;   // wave in block: 0..3
    const int lane = threadIdx.x & 63;
    const int grp  = lane >> 4;          // edge slot 0..3
    const int ci   = lane & 15;          // channel pair
    const int c2   = ci * 2;
    const int n    = bid * 4 + wib;      // dst node

    const int start = offs[n];
    const int end   = (n == NNODES - 1) ? NEDGES : offs[n + 1];
    const v2f bw = *(const v2f*)(Bw + c2);
    const float bb = Bb[0];
    const v2f pd = *(const v2f*)(pdst + n * 32 + c2);

    int e = start + grp;
    int2 rec = sorted2[(e < end) ? e : start];
    bool valid = (e < end);

    v2f acc = {0.f, 0.f};
    for (int e0 = start; e0 < end; e0 += 4) {
        int2 cur = rec;
        bool cv = valid;
        int en = e + 4;
        valid = (en < end);
        rec = sorted2[valid ? en : start];
        e = en;

        int s16 = cur.x;             // src*16
        int et  = cur.y & 0xffff;
        int el  = cur.y >> 16;

        v2f   ps = *(const v2f*)(psrc + s16 * 2 + c2);
        uint4 xq = xproj_b[s16 + ci];
        v2f t1v = bf2f(t1_s[(et << 4) + ci]);
        v2f t2v = bf2f(t2_s[(el << 4) + ci]);
        float4 c = c_s[et];

        v2f z = ps + pd + t1v + t2v;
        z.x = fmaxf(z.x, 0.f);
        z.y = fmaxf(z.y, 0.f);
        float d = fmaf(z.x, bw.x, z.y * bw.y);
        d = dpp_add<DPP_XOR1>(d);
        d = dpp_add<DPP_XOR2>(d);
        d = dpp_add<DPP_HMIR>(d);
        d = dpp_add<DPP_MIR>(d);
        float a = __builtin_amdgcn_rcpf(1.f + __expf(-(d + bb)));
        a = cv ? a : 0.f;

        v2f b0 = bf2f(xq.x), b1 = bf2f(xq.y), b2 = bf2f(xq.z), b3 = bf2f(xq.w);
        v2f m = c.x * b0 + c.y * b1 + c.z * b2 + c.w * b3;
        acc += a * m;
    }
    acc.x += __shfl_xor(acc.x, 16);
    acc.y += __shfl_xor(acc.y, 16);
    acc.x += __shfl_xor(acc.x, 32);
    acc.y += __shfl_xor(acc.y, 32);
    if (lane < 16) {
        v2f sp = *(const v2f*)(selfp + n * 32 + c2);
        v2f hv;
        hv.x = fmaxf(acc.x + sp.x, 0.f);
        hv.y = fmaxf(acc.y + sp.y, 0.f);
        *(v2f*)(h_next + n * 32 + c2) = hv;
    }
}

// ==================== per-graph mean (8 slices) + head/tail (y=8) ==========
__global__ __launch_bounds__(256) void mean_ht_k(
    const float* __restrict__ h, const int* __restrict__ head_ids,
    const int* __restrict__ tail_ids, float* __restrict__ g_acc,
    float* __restrict__ head_buf, float* __restrict__ tail_buf, int l)
{
    int g  = blockIdx.x;
    int sl = blockIdx.y;
    int i  = threadIdx.x & 31;
    if (sl == 8) {
        if (threadIdx.x < 32)
            head_buf[g*96 + l*32 + i] = h[head_ids[g]*32 + i];
        else if (threadIdx.x < 64)
            tail_buf[g*96 + l*32 + i] = h[tail_ids[g]*32 + i];
        return;
    }
    int sub = threadIdx.x >> 5;
    float acc = 0.f;
    for (int k = sub; k < 125; k += 8)
        acc += h[(g*NPER + sl*125 + k)*32 + i];
    __shared__ float red[8][32];
    red[sub][i] = acc;
    __syncthreads();
    if (threadIdx.x < 32) {
        float s2 = 0.f;
        #pragma unroll
        for (int k = 0; k < 8; k++) s2 += red[k][threadIdx.x];
        atomicAdd(&g_acc[g*96 + l*32 + threadIdx.x], s2 * (1.0f/NPER));
    }
}

// ==================== final readout ====================
__global__ __launch_bounds__(64) void readout_k(
    const float* __restrict__ g_acc, const float* __restrict__ head_buf,
    const float* __restrict__ tail_buf, const float* __restrict__ rel_tab,
    const int* __restrict__ rel_labels, const float* __restrict__ fc_w,
    const float* __restrict__ fc_b, float* __restrict__ out)
{
    int g = blockIdx.x;
    int t = threadIdx.x;
    float s = 0.f;
    for (int idx = t; idx < 320; idx += 64) {
        float v;
        if (idx < 96)       v = g_acc[g*96 + idx];
        else if (idx < 192) v = head_buf[g*96 + idx - 96];
        else if (idx < 288) v = tail_buf[g*96 + idx - 192];
        else                v = rel_tab[rel_labels[g]*32 + (idx - 288)];
        s += v * fc_w[idx];
    }
    s += __shfl_xor(s, 1, 64);
    s += __shfl_xor(s, 2, 64);
    s += __shfl_xor(s, 4, 64);
    s += __shfl_xor(s, 8, 64);
    s += __shfl_xor(s, 16, 64);
    s += __shfl_xor(s, 32, 64);
    if (t == 0) out[g] = s + fc_b[0];
}

extern "C" void kernel_launch(void* const* d_in, const int* in_sizes, int n_in,
                              void* d_out, int out_size, void* d_ws, size_t ws_size,
                              hipStream_t stream) {
    const float* feat        = (const float*)d_in[0];
    const float* basis       = (const float*)d_in[1];   // [3,4,32,32]
    const float* w_comp      = (const float*)d_in[2];   // [3,200,4]
    const float* self_loop_w = (const float*)d_in[3];   // [3,32,32]
    const float* A_w         = (const float*)d_in[4];   // [3,128,32]
    const float* A_b         = (const float*)d_in[5];   // [3,32]
    const float* B_w         = (const float*)d_in[6];   // [3,32,1]
    const float* B_b         = (const float*)d_in[7];   // [3,1]
    const float* attn_tab    = (const float*)d_in[8];   // [200,32]
    const float* rel_tab     = (const float*)d_in[9];   // [200,32]
    const float* fc_w        = (const float*)d_in[10];  // [320,1]
    const float* fc_b        = (const float*)d_in[11];  // [1]
    const int* src        = (const int*)d_in[12];
    const int* dst        = (const int*)d_in[13];
    const int* etype      = (const int*)d_in[14];
    const int* elabel     = (const int*)d_in[15];
    const int* head_ids   = (const int*)d_in[17];
    const int* tail_ids   = (const int*)d_in[18];
    const int* rel_labels = (const int*)d_in[19];

    float* ws = (float*)d_ws;
    size_t off = 0;
    float* h0    = ws + off; off += (size_t)NNODES * 32;
    float* h1    = ws + off; off += (size_t)NNODES * 32;
    uint4* xproj_b = (uint4*)(ws + off); off += (size_t)NNODES * 64;  // bf16 256B/node
    float* psrc  = ws + off; off += (size_t)NNODES * 32;
    float* pdst  = ws + off; off += (size_t)NNODES * 32;
    float* selfp = ws + off; off += (size_t)NNODES * 32;
    unsigned* t1b = (unsigned*)(ws + off); off += 3200;
    unsigned* t2b = (unsigned*)(ws + off); off += 3200;
    float* g_acc    = ws + off; off += NGRAPH * 96;
    float* head_buf = ws + off; off += NGRAPH * 96;
    float* tail_buf = ws + off; off += NGRAPH * 96;
    int* count  = (int*)(ws + off); off += NNODES;
    int* offs   = (int*)(ws + off); off += NNODES;
    int* cursor = (int*)(ws + off); off += NNODES;
    off = (off + 3) & ~(size_t)3;               // 16 B align
    int2* sorted2 = (int2*)(ws + off); off += (size_t)NEDGES * 2;

    // ---- one-time per call: CSR by dst + zero mean accumulator ----
    zero2_k<<<(NNODES + 255)/256, 256, 0, stream>>>(count, g_acc);
    hist_k<<<(NEDGES + 255)/256, 256, 0, stream>>>(dst, count);
    scan_k<<<NGRAPH, 1024, 0, stream>>>(count, offs, cursor);
    scatter_k<<<(NEDGES + 255)/256, 256, 0, stream>>>(src, dst, etype, elabel,
                                                      cursor, sorted2);

    const float* hcur = feat;
    float* hbufs[2] = { h0, h1 };
    for (int l = 0; l < 3; l++) {
        dim3 ngrid((NNODES + 255)/256, 7);
        node_k<<<ngrid, 256, 0, stream>>>(
            hcur, basis + (size_t)l*4096, self_loop_w + (size_t)l*1024,
            A_w + (size_t)l*4096, A_b + (size_t)l*32, attn_tab,
            xproj_b, psrc, pdst, selfp, t1b, t2b);
        float* hn = hbufs[l & 1];
        edge_csr_k<<<NNODES/4, 256, 0, stream>>>(
            sorted2, offs, psrc, pdst, t1b, t2b, xproj_b, selfp,
            w_comp + (size_t)l*800, B_w + (size_t)l*32, B_b + l, hn);
        dim3 mgrid(NGRAPH, 9);
        mean_ht_k<<<mgrid, 256, 0, stream>>>(
            hn, head_ids, tail_ids, g_acc, head_buf, tail_buf, l);
        hcur = hn;
    }
    readout_k<<<NGRAPH, 64, 0, stream>>>(
        g_acc, head_buf, tail_buf, rel_tab, rel_labels, fc_w, fc_b, (float*)d_out);
}

// Round 14
// 490.447 us; speedup vs baseline: 1.2795x; 1.2795x over previous
//
#include <hip/hip_runtime.h>

#define NGRAPH 100
#define NPER   1000
#define NNODES 100000
#define NEDGES 1600000
#define EPG    16000   // edges per graph

typedef float v2f __attribute__((ext_vector_type(2)));

// DPP-based add of a permuted lane within a 16-lane row; VALU latency.
template <int CTRL>
__device__ __forceinline__ float dpp_add(float x) {
    int yi = __builtin_amdgcn_update_dpp(0, __float_as_int(x), CTRL, 0xF, 0xF, true);
    return x + __int_as_float(yi);
}
#define DPP_XOR1 0xB1   // quad_perm [1,0,3,2]
#define DPP_XOR2 0x4E   // quad_perm [2,3,0,1]
#define DPP_HMIR 0x141  // row_half_mirror: completes an 8-lane sum

// bf16x2 (packed in u32) -> 2 floats
__device__ __forceinline__ v2f bf2f(unsigned u) {
    v2f r;
    r.x = __uint_as_float(u << 16);
    r.y = __uint_as_float(u & 0xffff0000u);
    return r;
}
// 2 floats -> bf16x2 (round-to-nearest-ish)
__device__ __forceinline__ unsigned pkbf(float a, float b) {
    unsigned ua = (__float_as_uint(a) + 0x8000u) >> 16;
    unsigned ub = (__float_as_uint(b) + 0x8000u) & 0xffff0000u;
    return ua | ub;
}

// ==================== utility: zero count + g_acc in one launch ============
__global__ __launch_bounds__(256) void zero2_k(int* __restrict__ count,
                                               float* __restrict__ g_acc) {
    int i = blockIdx.x * 256 + threadIdx.x;
    if (i < NNODES) count[i] = 0;
    if (i < NGRAPH * 96) g_acc[i] = 0.f;
}

// ==================== counting sort of edges by DST ====================
__global__ __launch_bounds__(256) void hist_k(const int* __restrict__ dst,
                                              int* __restrict__ count) {
    int e = blockIdx.x * 256 + threadIdx.x;
    if (e < NEDGES) atomicAdd(&count[dst[e]], 1);
}

__global__ __launch_bounds__(1024) void scan_k(const int* __restrict__ count,
                                               int* __restrict__ offs,
                                               int* __restrict__ cursor) {
    __shared__ int sc[1024];
    int t = threadIdx.x, g = blockIdx.x;
    int v = (t < NPER) ? count[g * NPER + t] : 0;
    sc[t] = v;
    __syncthreads();
    for (int s = 1; s < 1024; s <<= 1) {
        int add = (t >= s) ? sc[t - s] : 0;
        __syncthreads();
        sc[t] += add;
        __syncthreads();
    }
    if (t < NPER) {
        int start = g * EPG + sc[t] - v;   // exclusive
        offs[g * NPER + t]   = start;
        cursor[g * NPER + t] = start;
    }
}

// compressed record: {src*16, etype | elabel<<16}
__global__ __launch_bounds__(256) void scatter_k(
    const int* __restrict__ src, const int* __restrict__ dst,
    const int* __restrict__ et, const int* __restrict__ el,
    int* __restrict__ cursor, int2* __restrict__ sorted2) {
    int e = blockIdx.x * 256 + threadIdx.x;
    if (e >= NEDGES) return;
    int d = dst[e];
    int p = atomicAdd(&cursor[d], 1);
    sorted2[p] = make_int2(src[e] * 16, et[e] | (el[e] << 16));
}

// ==================== node projections: channel-sliced ====================
// grid (391, 7).
// y=0..3: xproj (bf16, pair-packed) channels [y*8,y*8+8) -> one 64B line.
// y=4,5:  psrc/pdst/selfp f32 channel halves -> full 64B line per matrix.
// y=6:    rel tables t1b/t2b (bf16 pairs).
__device__ __forceinline__ float4 dot32x4(const float* __restrict__ w,
                                          const float* hreg, int oc) {
    float4 a = {0.f, 0.f, 0.f, 0.f};
    #pragma unroll 4
    for (int d = 0; d < 32; d++) {
        float4 wv = *(const float4*)(w + d * 32 + oc * 4);
        a.x = fmaf(hreg[d], wv.x, a.x);
        a.y = fmaf(hreg[d], wv.y, a.y);
        a.z = fmaf(hreg[d], wv.z, a.z);
        a.w = fmaf(hreg[d], wv.w, a.w);
    }
    return a;
}

__global__ __launch_bounds__(256, 4) void node_k(
    const float* __restrict__ h, const float* __restrict__ basis_l,
    const float* __restrict__ selfw_l, const float* __restrict__ Aw_l,
    const float* __restrict__ Ab_l, const float* __restrict__ attn_tab,
    uint4* __restrict__ xproj_b, float* __restrict__ psrc,
    float* __restrict__ pdst, float* __restrict__ selfp,
    unsigned* __restrict__ t1b, unsigned* __restrict__ t2b)
{
    const int y = blockIdx.y;
    if (y == 6) {   // rel tables: r = bid*4 + wave, 64 threads per r
        int r = blockIdx.x * 4 + (threadIdx.x >> 6);
        if (r >= 200) return;
        int t = threadIdx.x & 63;
        int o = t & 31;
        bool second = t >= 32;
        const float* at = attn_tab + r * 32;
        const float* W  = Aw_l + (second ? 96*32 : 64*32);
        float acc = second ? 0.f : Ab_l[o];
        #pragma unroll 8
        for (int d = 0; d < 32; d++) acc += at[d] * W[d*32 + o];
        float nb = __shfl_down(acc, 1);
        unsigned u = pkbf(acc, nb);
        if (!(o & 1)) (second ? t2b : t1b)[r*16 + (o >> 1)] = u;
        return;
    }

    __shared__ float w_s[4096];
    if (y < 4) {
        const float4* b4 = (const float4*)basis_l;   // 1024 float4
        float4* w4 = (float4*)w_s;
        for (int k = threadIdx.x; k < 1024; k += 256) w4[k] = b4[k];
    } else {
        const float4* a4 = (const float4*)Aw_l;      // 512 float4 (rows 0..63)
        const float4* s4 = (const float4*)selfw_l;   // 256 float4
        float4* w4 = (float4*)w_s;
        for (int k = threadIdx.x; k < 768; k += 256)
            w4[k] = (k < 512) ? a4[k] : s4[k - 512];
    }
    __syncthreads();

    int n = blockIdx.x * 256 + threadIdx.x;
    if (n >= NNODES) return;

    float hreg[32];
    {
        const float4* hp = (const float4*)(h + n * 32);
        #pragma unroll
        for (int k = 0; k < 8; k++) {
            float4 v = hp[k];
            hreg[4*k+0]=v.x; hreg[4*k+1]=v.y; hreg[4*k+2]=v.z; hreg[4*k+3]=v.w;
        }
    }

    if (y < 4) {
        uint4* xob = xproj_b + n * 16 + y * 4;
        #pragma unroll 1
        for (int ocl = 0; ocl < 2; ocl++) {
            const int oc = y * 2 + ocl;
            float4 p[4];
            #pragma unroll 1
            for (int b = 0; b < 4; b++)
                p[b] = dot32x4(w_s + b * 1024, hreg, oc);
            // pair-pack bf16: dword k = basis k pair {j0,j1}
            xob[ocl*2+0] = make_uint4(pkbf(p[0].x,p[0].y), pkbf(p[1].x,p[1].y),
                                      pkbf(p[2].x,p[2].y), pkbf(p[3].x,p[3].y));
            xob[ocl*2+1] = make_uint4(pkbf(p[0].z,p[0].w), pkbf(p[1].z,p[1].w),
                                      pkbf(p[2].z,p[2].w), pkbf(p[3].z,p[3].w));
        }
    } else {
        const int oc0 = (y - 4) * 4;
        #pragma unroll 1
        for (int m = 0; m < 3; m++) {
            const float* wbase = w_s + (m < 2 ? m * 1024 : 2048);
            float* outp = (m == 0 ? psrc : m == 1 ? pdst : selfp);
            float4 r[4];
            #pragma unroll 1
            for (int ocl = 0; ocl < 4; ocl++)
                r[ocl] = dot32x4(wbase, hreg, oc0 + ocl);
            float* o = outp + n * 32 + oc0 * 4;   // 64B line
            *(float4*)(o +  0) = r[0];
            *(float4*)(o +  4) = r[1];
            *(float4*)(o +  8) = r[2];
            *(float4*)(o + 12) = r[3];
        }
    }
}

// ==================== CSR edge kernel: 8 lanes/edge, 4 ch/lane =============
// R14: wave = 1 node, 8 edge-slots x 8 lanes. Same 7 vector-mem instructions
// per iteration now cover 8 edges instead of 4 -> gather-instruction count
// per edge halves (R10/R12/R13 nulls point at TA address-processing as the
// binding resource). Reduce = 3 DPP steps. No LDS (R13 occupancy lesson).
__global__ __launch_bounds__(256) void edge_csr_k(
    const int2* __restrict__ sorted2, const int* __restrict__ offs,
    const float* __restrict__ psrc, const float* __restrict__ pdst,
    const unsigned* __restrict__ t1b, const unsigned* __restrict__ t2b,
    const uint4* __restrict__ xproj_b, const float* __restrict__ selfp,
    const float* __restrict__ wcomp_l,
    const float* __restrict__ Bw, const float* __restrict__ Bb,
    float* __restrict__ h_next)
{
    // XCD-bijective swizzle: 25000 blocks, 25000 % 8 == 0.
    const int CPX = 25000 / 8;
    int bid = (int)blockIdx.x;
    bid = (bid % 8) * CPX + bid / 8;

    const int wib  = threadIdx.x >> 6;   // wave in block: 0..3
    const int lane = threadIdx.x & 63;
    const int grp  = lane >> 3;          // edge slot 0..7
    const int ci   = lane & 7;           // channel quad 0..7
    const int c4   = ci * 4;
    const int n    = bid * 4 + wib;      // dst node

    const int start = offs[n];
    const int end   = (n == NNODES - 1) ? NEDGES : offs[n + 1];
    const float4 bw = *(const float4*)(Bw + c4);
    const float bb = Bb[0];
    const float4 pd = *(const float4*)(pdst + n * 32 + c4);

    int e = start + grp;
    int2 rec = sorted2[(e < end) ? e : start];
    bool valid = (e < end);

    v2f acc01 = {0.f, 0.f}, acc23 = {0.f, 0.f};
    for (int e0 = start; e0 < end; e0 += 8) {
        int2 cur = rec;
        bool cv = valid;
        int en = e + 8;
        valid = (en < end);
        rec = sorted2[valid ? en : start];
        e = en;

        int s16 = cur.x;             // src*16 (uint4 index base)
        int et  = cur.y & 0xffff;
        int el  = cur.y >> 16;

        float4 ps  = *(const float4*)(psrc + s16 * 2 + c4);
        uint4  xlo = xproj_b[s16 + ci * 2];
        uint4  xhi = xproj_b[s16 + ci * 2 + 1];
        uint2  t1u = *(const uint2*)(t1b + et * 16 + ci * 2);
        uint2  t2u = *(const uint2*)(t2b + el * 16 + ci * 2);
        float4 c   = *(const float4*)(wcomp_l + et * 4);

        v2f t1a = bf2f(t1u.x), t1c = bf2f(t1u.y);
        v2f t2a = bf2f(t2u.x), t2c = bf2f(t2u.y);
        float z0 = fmaxf(ps.x + pd.x + t1a.x + t2a.x, 0.f);
        float z1 = fmaxf(ps.y + pd.y + t1a.y + t2a.y, 0.f);
        float z2 = fmaxf(ps.z + pd.z + t1c.x + t2c.x, 0.f);
        float z3 = fmaxf(ps.w + pd.w + t1c.y + t2c.y, 0.f);
        float d = fmaf(z0, bw.x, fmaf(z1, bw.y, fmaf(z2, bw.z, z3 * bw.w)));
        d = dpp_add<DPP_XOR1>(d);
        d = dpp_add<DPP_XOR2>(d);
        d = dpp_add<DPP_HMIR>(d);
        float a = __builtin_amdgcn_rcpf(1.f + __expf(-(d + bb)));
        a = cv ? a : 0.f;

        v2f b0 = bf2f(xlo.x), b1 = bf2f(xlo.y), b2 = bf2f(xlo.z), b3 = bf2f(xlo.w);
        v2f m01 = c.x * b0 + c.y * b1 + c.z * b2 + c.w * b3;
        v2f g0 = bf2f(xhi.x), g1 = bf2f(xhi.y), g2 = bf2f(xhi.z), g3 = bf2f(xhi.w);
        v2f m23 = c.x * g0 + c.y * g1 + c.z * g2 + c.w * g3;
        acc01 += a * m01;
        acc23 += a * m23;
    }
    // reduce across the 8 edge-slots (off the hot loop)
    #pragma unroll
    for (int s = 8; s <= 32; s <<= 1) {
        acc01.x += __shfl_xor(acc01.x, s);
        acc01.y += __shfl_xor(acc01.y, s);
        acc23.x += __shfl_xor(acc23.x, s);
        acc23.y += __shfl_xor(acc23.y, s);
    }
    if (lane < 8) {
        float4 sp = *(const float4*)(selfp + n * 32 + c4);
        float4 hv;
        hv.x = fmaxf(acc01.x + sp.x, 0.f);
        hv.y = fmaxf(acc01.y + sp.y, 0.f);
        hv.z = fmaxf(acc23.x + sp.z, 0.f);
        hv.w = fmaxf(acc23.y + sp.w, 0.f);
        *(float4*)(h_next + n * 32 + c4) = hv;
    }
}

// ==================== per-graph mean (8 slices) + head/tail (y=8) ==========
__global__ __launch_bounds__(256) void mean_ht_k(
    const float* __restrict__ h, const int* __restrict__ head_ids,
    const int* __restrict__ tail_ids, float* __restrict__ g_acc,
    float* __restrict__ head_buf, float* __restrict__ tail_buf, int l)
{
    int g  = blockIdx.x;
    int sl = blockIdx.y;
    int i  = threadIdx.x & 31;
    if (sl == 8) {
        if (threadIdx.x < 32)
            head_buf[g*96 + l*32 + i] = h[head_ids[g]*32 + i];
        else if (threadIdx.x < 64)
            tail_buf[g*96 + l*32 + i] = h[tail_ids[g]*32 + i];
        return;
    }
    int sub = threadIdx.x >> 5;
    float acc = 0.f;
    for (int k = sub; k < 125; k += 8)
        acc += h[(g*NPER + sl*125 + k)*32 + i];
    __shared__ float red[8][32];
    red[sub][i] = acc;
    __syncthreads();
    if (threadIdx.x < 32) {
        float s2 = 0.f;
        #pragma unroll
        for (int k = 0; k < 8; k++) s2 += red[k][threadIdx.x];
        atomicAdd(&g_acc[g*96 + l*32 + threadIdx.x], s2 * (1.0f/NPER));
    }
}

// ==================== final readout ====================
__global__ __launch_bounds__(64) void readout_k(
    const float* __restrict__ g_acc, const float* __restrict__ head_buf,
    const float* __restrict__ tail_buf, const float* __restrict__ rel_tab,
    const int* __restrict__ rel_labels, const float* __restrict__ fc_w,
    const float* __restrict__ fc_b, float* __restrict__ out)
{
    int g = blockIdx.x;
    int t = threadIdx.x;
    float s = 0.f;
    for (int idx = t; idx < 320; idx += 64) {
        float v;
        if (idx < 96)       v = g_acc[g*96 + idx];
        else if (idx < 192) v = head_buf[g*96 + idx - 96];
        else if (idx < 288) v = tail_buf[g*96 + idx - 192];
        else                v = rel_tab[rel_labels[g]*32 + (idx - 288)];
        s += v * fc_w[idx];
    }
    s += __shfl_xor(s, 1, 64);
    s += __shfl_xor(s, 2, 64);
    s += __shfl_xor(s, 4, 64);
    s += __shfl_xor(s, 8, 64);
    s += __shfl_xor(s, 16, 64);
    s += __shfl_xor(s, 32, 64);
    if (t == 0) out[g] = s + fc_b[0];
}

extern "C" void kernel_launch(void* const* d_in, const int* in_sizes, int n_in,
                              void* d_out, int out_size, void* d_ws, size_t ws_size,
                              hipStream_t stream) {
    const float* feat        = (const float*)d_in[0];
    const float* basis       = (const float*)d_in[1];   // [3,4,32,32]
    const float* w_comp      = (const float*)d_in[2];   // [3,200,4]
    const float* self_loop_w = (const float*)d_in[3];   // [3,32,32]
    const float* A_w         = (const float*)d_in[4];   // [3,128,32]
    const float* A_b         = (const float*)d_in[5];   // [3,32]
    const float* B_w         = (const float*)d_in[6];   // [3,32,1]
    const float* B_b         = (const float*)d_in[7];   // [3,1]
    const float* attn_tab    = (const float*)d_in[8];   // [200,32]
    const float* rel_tab     = (const float*)d_in[9];   // [200,32]
    const float* fc_w        = (const float*)d_in[10];  // [320,1]
    const float* fc_b        = (const float*)d_in[11];  // [1]
    const int* src        = (const int*)d_in[12];
    const int* dst        = (const int*)d_in[13];
    const int* etype      = (const int*)d_in[14];
    const int* elabel     = (const int*)d_in[15];
    const int* head_ids   = (const int*)d_in[17];
    const int* tail_ids   = (const int*)d_in[18];
    const int* rel_labels = (const int*)d_in[19];

    float* ws = (float*)d_ws;
    size_t off = 0;
    float* h0    = ws + off; off += (size_t)NNODES * 32;
    float* h1    = ws + off; off += (size_t)NNODES * 32;
    uint4* xproj_b = (uint4*)(ws + off); off += (size_t)NNODES * 64;  // bf16 256B/node
    float* psrc  = ws + off; off += (size_t)NNODES * 32;
    float* pdst  = ws + off; off += (size_t)NNODES * 32;
    float* selfp = ws + off; off += (size_t)NNODES * 32;
    unsigned* t1b = (unsigned*)(ws + off); off += 3200;
    unsigned* t2b = (unsigned*)(ws + off); off += 3200;
    float* g_acc    = ws + off; off += NGRAPH * 96;
    float* head_buf = ws + off; off += NGRAPH * 96;
    float* tail_buf = ws + off; off += NGRAPH * 96;
    int* count  = (int*)(ws + off); off += NNODES;
    int* offs   = (int*)(ws + off); off += NNODES;
    int* cursor = (int*)(ws + off); off += NNODES;
    off = (off + 3) & ~(size_t)3;               // 16 B align
    int2* sorted2 = (int2*)(ws + off); off += (size_t)NEDGES * 2;

    // ---- one-time per call: CSR by dst + zero mean accumulator ----
    zero2_k<<<(NNODES + 255)/256, 256, 0, stream>>>(count, g_acc);
    hist_k<<<(NEDGES + 255)/256, 256, 0, stream>>>(dst, count);
    scan_k<<<NGRAPH, 1024, 0, stream>>>(count, offs, cursor);
    scatter_k<<<(NEDGES + 255)/256, 256, 0, stream>>>(src, dst, etype, elabel,
                                                      cursor, sorted2);

    const float* hcur = feat;
    float* hbufs[2] = { h0, h1 };
    for (int l = 0; l < 3; l++) {
        dim3 ngrid((NNODES + 255)/256, 7);
        node_k<<<ngrid, 256, 0, stream>>>(
            hcur, basis + (size_t)l*4096, self_loop_w + (size_t)l*1024,
            A_w + (size_t)l*4096, A_b + (size_t)l*32, attn_tab,
            xproj_b, psrc, pdst, selfp, t1b, t2b);
        float* hn = hbufs[l & 1];
        edge_csr_k<<<NNODES/4, 256, 0, stream>>>(
            sorted2, offs, psrc, pdst, t1b, t2b, xproj_b, selfp,
            w_comp + (size_t)l*800, B_w + (size_t)l*32, B_b + l, hn);
        dim3 mgrid(NGRAPH, 9);
        mean_ht_k<<<mgrid, 256, 0, stream>>>(
            hn, head_ids, tail_ids, g_acc, head_buf, tail_buf, l);
        hcur = hn;
    }
    readout_k<<<NGRAPH, 64, 0, stream>>>(
        g_acc, head_buf, tail_buf, rel_tab, rel_labels, fc_w, fc_b, (float*)d_out);
}